// Round 10
// baseline (180.295 us; speedup 1.0000x reference)
//
#include <hip/hip_runtime.h>
#include <hip/hip_bf16.h>

// GraphSAGE 2-layer forward, bf16-MFMA inner pipeline.
// R10: buildagg+gemm12 fused into bag_k — the layer-1 agg tile lives ONLY in LDS
//      (AG[128][136]); phase-1 k<128 A-operand reads AG directly (no staging DMA,
//      no aggb buffer: -38 MB HBM round-trip, -1 dispatch). ~104 KB LDS, 1 blk/CU.
// Dispatches: memset(1.5KB) -> entry -> bag -> final.

#define N_NODES 50000
#define N_EDGES 800000
#define M_PAD   50048   // 391 * 128

#define BUCK_SHIFT 7
#define K_BUCK 391            // ceil(50000/128)
#define BUCK_CAP 4096         // bucket edges: mean 2046, sigma ~45 (guarded anyway)
#define CSR_SEG 4608          // fixed per-bucket csr region (>= BUCK_CAP + 128*3 pad)
#define P1_EPB 16             // edges per thread in partition phase (4096/block)
#define P_BLOCKS 196          // ceil(800000/4096)
#define PREP_ELEMS (N_NODES * 64 + 98304)   // 3298304 = 12884*256 exactly

typedef unsigned int uint;
typedef unsigned short ushort;
typedef __attribute__((ext_vector_type(8))) short short8;
typedef __attribute__((ext_vector_type(4))) float floatx4;

__device__ __forceinline__ ushort f2bf(float f) {
    union { float f; uint u; } c; c.f = f;
    uint u = c.u;
    return (ushort)((u + 0x7FFFu + ((u >> 16) & 1u)) >> 16);  // RNE
}
__device__ __forceinline__ uint pack2(float lo, float hi) {
    return (uint)f2bf(lo) | ((uint)f2bf(hi) << 16);
}
__device__ __forceinline__ float bflo(uint v) { return __uint_as_float(v << 16); }
__device__ __forceinline__ float bfhi(uint v) { return __uint_as_float(v & 0xffff0000u); }
__device__ __forceinline__ void gload_lds16(const ushort* g, ushort* l) {
    __builtin_amdgcn_global_load_lds(
        (const __attribute__((address_space(1))) void*)g,
        (__attribute__((address_space(3))) void*)l, 16, 0, 0);
}

#define ACC8(A, v) { A[0] += bflo(v.x); A[1] += bfhi(v.x); A[2] += bflo(v.y); A[3] += bfhi(v.y); \
                     A[4] += bflo(v.z); A[5] += bfhi(v.z); A[6] += bflo(v.w); A[7] += bfhi(v.w); }

// ---------------- entry: partition (blocks < P_BLOCKS) + dtype prep ----------------

__global__ __launch_bounds__(256) void entry_k(
        const int* __restrict__ ei, int* __restrict__ bucket_cnt, int* __restrict__ part,
        const float2* __restrict__ x2, uint* __restrict__ xb,
        const float* __restrict__ W1l, const float* __restrict__ W1r,
        const float* __restrict__ W2l, const float* __restrict__ W2r,
        ushort* __restrict__ B1, ushort* __restrict__ B2) {
    __shared__ int hist[K_BUCK];
    __shared__ int goff[K_BUCK];
    const int tid = threadIdx.x;
    if (blockIdx.x < P_BLOCKS) {
        for (int i = tid; i < K_BUCK; i += 256) hist[i] = 0;
        __syncthreads();
        const int e0 = blockIdx.x * (256 * P1_EPB);
        int srcv[P1_EPB], dstv[P1_EPB];
        #pragma unroll
        for (int i = 0; i < P1_EPB; ++i) {
            int e = e0 + tid + (i << 8);
            bool ok = e < N_EDGES;
            srcv[i] = ok ? ei[e] : 0;
            dstv[i] = ok ? ei[N_EDGES + e] : -1;
            if (ok) atomicAdd(&hist[dstv[i] >> BUCK_SHIFT], 1);
        }
        __syncthreads();
        for (int b = tid; b < K_BUCK; b += 256) {
            int c = hist[b];
            goff[b] = c ? atomicAdd(&bucket_cnt[b], c) : 0;
            hist[b] = 0;                    // reuse as block-local cursor
        }
        __syncthreads();
        #pragma unroll
        for (int i = 0; i < P1_EPB; ++i) {
            if (dstv[i] >= 0) {
                int b = dstv[i] >> BUCK_SHIFT;
                int pos = goff[b] + atomicAdd(&hist[b], 1);
                if (pos < BUCK_CAP)         // memory-safety guard
                    part[(size_t)b * BUCK_CAP + pos] = srcv[i] | ((dstv[i] & 127) << 16);
            }
        }
        return;
    }
    int i = (blockIdx.x - P_BLOCKS) * 256 + tid;
    if (i < N_NODES * 64) {
        float2 v = x2[i];
        xb[i] = pack2(v.x, v.y);
        return;
    }
    int t = i - N_NODES * 64;
    if (t < 65536) {                        // B1[n][k], n<256, k<256
        int n = t >> 8, k = t & 255;
        float v = (k < 128) ? W1l[n * 128 + k] : W1r[n * 128 + (k - 128)];
        B1[t] = f2bf(v);
    } else if (t < 98304) {                 // B2[n][k], n<128, k<256
        int t2 = t - 65536;
        int n = t2 >> 8, k = t2 & 255;
        float v = (n < 64) ? W2l[n * 256 + k] : W2r[(n - 64) * 256 + k];
        B2[t2] = f2bf(v);
    }
}

// ---------------- bag: CSR build + agg gather (LDS tile) + fused 2-layer GEMM ----------------
// grid = 391, 512 threads = 8 waves. LDS (ushort units):
//   Hs  @0      [128][136]  h1-half tile (epilogue-1 park)
//   AG  @17408  [128][136]  layer-1 agg tile (gather output; phase-1 A for k<128)
//   ST  @34816  2 x 8192    ping-pong stage buffers (A-panel@+0, B-panel@+4096);
//                           csr_l (4608) aliases ST during build/gather phase.
// Phase-1 (per half h): 8 BK=32 panels; k<128 A from AG (no DMA), k>=128 A staged
// from xb; B1 always staged; ping-pong so DMA overlaps MFMA. Phase-2: B2-half
// staged once into ST (overlaps Hs epilogue), 4 panels from LDS.

#define HS_STRIDE 136
#define AG_OFF 17408
#define AG_STRIDE 136
#define ST_OFF 34816

__global__ __launch_bounds__(512) void bag_k(
        const int* __restrict__ part, const int* __restrict__ bucket_cnt,
        int* __restrict__ rs, int* __restrict__ deg_g, float* __restrict__ inv,
        ushort* __restrict__ csr16, const uint* __restrict__ xb,
        const ushort* __restrict__ B1, const ushort* __restrict__ B2,
        const float* __restrict__ b1, ushort* __restrict__ t2,
        ushort* __restrict__ u2b) {
    __shared__ __align__(16) ushort lds[ST_OFF + 16384];
    __shared__ int degl[128], rsl[128], cur[128];
    ushort* csr_l = &lds[ST_OFF];           // alias: dead before GEMM staging begins
    const int b = blockIdx.x;
    const int tid = threadIdx.x;
    const int bm = b << 7;

    // ---- build ----
    if (tid < 128) { degl[tid] = 0; cur[tid] = 0; }
    for (int i = tid; i < CSR_SEG; i += 512) csr_l[i] = 0;
    int Eb = bucket_cnt[b]; if (Eb > BUCK_CAP) Eb = BUCK_CAP;
    const int* pe = part + (size_t)b * BUCK_CAP;
    __syncthreads();
    for (int i = tid; i < Eb; i += 512)
        atomicAdd(&degl[pe[i] >> 16], 1);
    __syncthreads();
    if (tid < 64) {                          // wave 0: exclusive scan of x4-padded degs
        int carry = 0;
        for (int c = 0; c < 128; c += 64) {
            int v = (degl[c + tid] + 3) & ~3;
            int sc = v;
            #pragma unroll
            for (int off = 1; off < 64; off <<= 1) {
                int t = __shfl_up(sc, off);
                if (tid >= off) sc += t;
            }
            rsl[c + tid] = carry + sc - v;
            carry += __shfl(sc, 63);
        }
    }
    __syncthreads();
    if (tid < 128) {
        int n = bm + tid;
        if (n < N_NODES) {
            rs[n] = b * CSR_SEG + rsl[tid];
            deg_g[n] = degl[tid];
            inv[n] = 1.0f / fmaxf((float)degl[tid], 1.0f);
        }
    }
    __syncthreads();
    for (int i = tid; i < Eb; i += 512) {
        int e = pe[i];
        int ld = e >> 16;
        int pos = atomicAdd(&cur[ld], 1);
        int o = rsl[ld] + pos;
        ushort s = (ushort)(e & 0xFFFF);
        csr_l[o] = s;
        csr16[(size_t)b * CSR_SEG + o] = s;
    }
    __syncthreads();

    // ---- gather into AG (node pairs, 8 loads in flight per 16-lane group) ----
    {
        const int g = tid >> 4, sub = tid & 15;
        #pragma unroll
        for (int v = 0; v < 4; v += 2) {
            const int ln0 = g * 4 + v, ln1 = ln0 + 1;
            const int n0 = bm + ln0, n1 = n0 + 1;
            if (n0 >= N_NODES) continue;
            const int beg0 = rsl[ln0], cnt0 = degl[ln0];
            const int beg1 = rsl[ln1], cnt1 = (n1 < N_NODES) ? degl[ln1] : 0;
            float A0[8] = {}, A1[8] = {};
            const int maxc = cnt0 > cnt1 ? cnt0 : cnt1;
            const int nR = (maxc + 3) >> 2;
            #pragma unroll 2
            for (int r = 0; r < nR; ++r) {
                uint2 i0 = *(const uint2*)&csr_l[beg0 + (r << 2)];
                uint2 i1 = *(const uint2*)&csr_l[beg1 + (r << 2)];
                uint4 v00 = *(const uint4*)(xb + (size_t)(i0.x & 0xFFFF) * 64 + (sub << 2));
                uint4 v01 = *(const uint4*)(xb + (size_t)(i0.x >> 16)    * 64 + (sub << 2));
                uint4 v02 = *(const uint4*)(xb + (size_t)(i0.y & 0xFFFF) * 64 + (sub << 2));
                uint4 v03 = *(const uint4*)(xb + (size_t)(i0.y >> 16)    * 64 + (sub << 2));
                uint4 v10 = *(const uint4*)(xb + (size_t)(i1.x & 0xFFFF) * 64 + (sub << 2));
                uint4 v11 = *(const uint4*)(xb + (size_t)(i1.x >> 16)    * 64 + (sub << 2));
                uint4 v12 = *(const uint4*)(xb + (size_t)(i1.y & 0xFFFF) * 64 + (sub << 2));
                uint4 v13 = *(const uint4*)(xb + (size_t)(i1.y >> 16)    * 64 + (sub << 2));
                int e0 = r << 2;
                if (e0 + 0 < cnt0) ACC8(A0, v00);
                if (e0 + 1 < cnt0) ACC8(A0, v01);
                if (e0 + 2 < cnt0) ACC8(A0, v02);
                if (e0 + 3 < cnt0) ACC8(A0, v03);
                if (e0 + 0 < cnt1) ACC8(A1, v10);
                if (e0 + 1 < cnt1) ACC8(A1, v11);
                if (e0 + 2 < cnt1) ACC8(A1, v12);
                if (e0 + 3 < cnt1) ACC8(A1, v13);
            }
            {
                const float w = 1.0f / fmaxf((float)cnt0, 1.0f);
                uint4 o;
                o.x = pack2(A0[0] * w, A0[1] * w); o.y = pack2(A0[2] * w, A0[3] * w);
                o.z = pack2(A0[4] * w, A0[5] * w); o.w = pack2(A0[6] * w, A0[7] * w);
                *(uint4*)((uint*)&lds[AG_OFF + ln0 * AG_STRIDE] + (sub << 2)) = o;
            }
            if (n1 < N_NODES) {
                const float w = 1.0f / fmaxf((float)cnt1, 1.0f);
                uint4 o;
                o.x = pack2(A1[0] * w, A1[1] * w); o.y = pack2(A1[2] * w, A1[3] * w);
                o.z = pack2(A1[4] * w, A1[5] * w); o.w = pack2(A1[6] * w, A1[7] * w);
                *(uint4*)((uint*)&lds[AG_OFF + ln1 * AG_STRIDE] + (sub << 2)) = o;
            }
        }
    }
    __syncthreads();                          // AG ready; csr_l dead from here

    // ---- GEMM (fused 2-layer) ----
    const int w8 = tid >> 6, lane = tid & 63;
    const int q = lane >> 4, mr = lane & 15;
    const int wm = (w8 & 1) << 6;             // wave rows 0/64
    const int wn = (w8 >> 1) << 5;            // wave cols 0/32/64/96
    const int srow = tid >> 2;                // staging row 0..127
    const int scol = (tid & 3) << 3;          // ushort offset within 32-wide panel

    auto stage = [&](int h, int p, int buf) {
        const int k0 = p << 5;
        if (k0 >= 128)                        // A from xb only for k>=128 (k<128 = AG in LDS)
            gload_lds16((const ushort*)xb + (size_t)(bm + srow) * 128 + (k0 - 128) + scol,
                        lds + ST_OFF + (buf << 13) + srow * 32 + scol);
        gload_lds16(B1 + (size_t)((h << 7) + srow) * 256 + k0 + scol,
                    lds + ST_OFF + (buf << 13) + 4096 + srow * 32 + scol);
    };

    floatx4 acc2[4][2];
    #pragma unroll
    for (int i = 0; i < 4; ++i)
        #pragma unroll
        for (int j = 0; j < 2; ++j)
            acc2[i][j] = (floatx4){0.f, 0.f, 0.f, 0.f};

    #pragma unroll
    for (int h = 0; h < 2; ++h) {
        floatx4 acc1[4][2];
        #pragma unroll
        for (int i = 0; i < 4; ++i)
            #pragma unroll
            for (int j = 0; j < 2; ++j)
                acc1[i][j] = (floatx4){0.f, 0.f, 0.f, 0.f};
        stage(h, 0, 0);
        #pragma unroll
        for (int p = 0; p < 8; ++p) {
            __syncthreads();
            if (p < 7) stage(h, p + 1, (p + 1) & 1);
            const int buf = p & 1;
            short8 af[4], bfr[2];
            if (p < 4) {
                #pragma unroll
                for (int i = 0; i < 4; ++i)
                    af[i] = *(const short8*)&lds[AG_OFF + (wm + (i << 4) + mr) * AG_STRIDE + (p << 5) + (q << 3)];
            } else {
                #pragma unroll
                for (int i = 0; i < 4; ++i)
                    af[i] = *(const short8*)&lds[ST_OFF + (buf << 13) + (wm + (i << 4) + mr) * 32 + (q << 3)];
            }
            #pragma unroll
            for (int j = 0; j < 2; ++j)
                bfr[j] = *(const short8*)&lds[ST_OFF + (buf << 13) + 4096 + (wn + (j << 4) + mr) * 32 + (q << 3)];
            #pragma unroll
            for (int i = 0; i < 4; ++i)
                #pragma unroll
                for (int j = 0; j < 2; ++j)
                    acc1[i][j] = __builtin_amdgcn_mfma_f32_16x16x32_bf16(af[i], bfr[j], acc1[i][j], 0, 0, 0);
        }
        __syncthreads();                      // ST reads done; free for B2
        #pragma unroll
        for (int p2 = 0; p2 < 4; ++p2)        // B2-half fills both ST buffers (overlaps epilogue)
            gload_lds16(B2 + (size_t)srow * 256 + (h << 7) + (p2 << 5) + scol,
                        lds + ST_OFF + (p2 << 12) + srow * 32 + scol);
        #pragma unroll
        for (int i = 0; i < 4; ++i) {         // epilogue 1: relu+bias -> Hs (bf16)
            int row = wm + (i << 4) + (q << 2);
            #pragma unroll
            for (int j = 0; j < 2; ++j) {
                int col = wn + (j << 4) + mr;
                float bv = b1[(h << 7) + col];
                #pragma unroll
                for (int r = 0; r < 4; ++r) {
                    float v = fmaxf(acc1[i][j][r] + bv, 0.f);
                    lds[(row + r) * HS_STRIDE + col] = f2bf(v);
                }
            }
        }
        __syncthreads();
        #pragma unroll
        for (int p2 = 0; p2 < 4; ++p2) {      // phase 2: acc2 += Hs @ B2half^T
            short8 af2[4], bf2[2];
            #pragma unroll
            for (int i = 0; i < 4; ++i)
                af2[i] = *(const short8*)&lds[(wm + (i << 4) + mr) * HS_STRIDE + (p2 << 5) + (q << 3)];
            #pragma unroll
            for (int j = 0; j < 2; ++j)
                bf2[j] = *(const short8*)&lds[ST_OFF + (p2 << 12) + (wn + (j << 4) + mr) * 32 + (q << 3)];
            #pragma unroll
            for (int i = 0; i < 4; ++i)
                #pragma unroll
                for (int j = 0; j < 2; ++j)
                    acc2[i][j] = __builtin_amdgcn_mfma_f32_16x16x32_bf16(af2[i], bf2[j], acc2[i][j], 0, 0, 0);
        }
        __syncthreads();                      // ST free before next h's staging
    }
    // ---- epilogue 2: t2 (cols 0..63) | u2 (cols 64..127), both bf16 ----
    #pragma unroll
    for (int i = 0; i < 4; ++i) {
        int row = bm + wm + (i << 4) + (q << 2);
        #pragma unroll
        for (int j = 0; j < 2; ++j) {
            int col = wn + (j << 4) + mr;
            #pragma unroll
            for (int r = 0; r < 4; ++r) {
                float v = acc2[i][j][r];
                if (col < 64) t2[(size_t)(row + r) * 64 + col] = f2bf(v);
                else          u2b[(size_t)(row + r) * 64 + (col - 64)] = f2bf(v);
            }
        }
    }
}

// ---------------- final: group-per-node (8 lanes), broadcast idx, no reduce ----------------

__global__ __launch_bounds__(256) void final_k(
        const int* __restrict__ rs, const int* __restrict__ deg,
        const ushort* __restrict__ csr16, const uint* __restrict__ t2,
        const uint* __restrict__ u2, const float* __restrict__ b2,
        const float* __restrict__ inv, float* __restrict__ out) {
    const int tid = threadIdx.x, lane = tid & 63, wid = tid >> 6;
    const int g = lane >> 3, sub = lane & 7;
    const int n = blockIdx.x * 32 + wid * 8 + g;
    if (n >= N_NODES) return;
    const int beg = rs[n], cnt = deg[n];
    float A[8] = {};
    const int nR = (cnt + 3) >> 2;
    #pragma unroll 4
    for (int r = 0; r < nR; ++r) {
        uint2 i2 = *(const uint2*)(csr16 + beg + (r << 2));     // 4 src ids, broadcast
        int s0 = i2.x & 0xFFFF, s1 = i2.x >> 16;
        int s2 = i2.y & 0xFFFF, s3 = i2.y >> 16;
        uint4 v0 = *(const uint4*)(t2 + (size_t)s0 * 32 + (sub << 2));
        uint4 v1 = *(const uint4*)(t2 + (size_t)s1 * 32 + (sub << 2));
        uint4 v2 = *(const uint4*)(t2 + (size_t)s2 * 32 + (sub << 2));
        uint4 v3 = *(const uint4*)(t2 + (size_t)s3 * 32 + (sub << 2));
        int e0 = r << 2;
        if (e0 + 0 < cnt) ACC8(A, v0);
        if (e0 + 1 < cnt) ACC8(A, v1);
        if (e0 + 2 < cnt) ACC8(A, v2);
        if (e0 + 3 < cnt) ACC8(A, v3);
    }
    const float w = inv[n];
    uint4 ur = *(const uint4*)(u2 + (size_t)n * 32 + (sub << 2));
    const float* br = b2 + (sub << 3);
    float4 o0, o1;
    o0.x = bflo(ur.x) + br[0] + A[0] * w;
    o0.y = bfhi(ur.x) + br[1] + A[1] * w;
    o0.z = bflo(ur.y) + br[2] + A[2] * w;
    o0.w = bfhi(ur.y) + br[3] + A[3] * w;
    o1.x = bflo(ur.z) + br[4] + A[4] * w;
    o1.y = bfhi(ur.z) + br[5] + A[5] * w;
    o1.z = bflo(ur.w) + br[6] + A[6] * w;
    o1.w = bfhi(ur.w) + br[7] + A[7] * w;
    float* orow = out + (size_t)n * 64 + (sub << 3);
    *(float4*)orow = o0;
    *(float4*)(orow + 4) = o1;
}

// ---------------- launch ----------------

extern "C" void kernel_launch(void* const* d_in, const int* in_sizes, int n_in,
                              void* d_out, int out_size, void* d_ws, size_t ws_size,
                              hipStream_t stream) {
    const float* x   = (const float*)d_in[0];
    const int*   ei  = (const int*)d_in[1];
    const float* W1l = (const float*)d_in[2];
    const float* W1r = (const float*)d_in[3];
    const float* b1  = (const float*)d_in[4];
    const float* W2l = (const float*)d_in[5];
    const float* W2r = (const float*)d_in[6];
    const float* b2  = (const float*)d_in[7];
    float* out = (float*)d_out;

    char* base = (char*)d_ws;
    size_t off = 0;
    auto alloc = [&](size_t bytes) -> void* {
        void* p = base + off;
        off = (off + bytes + 255) & ~(size_t)255;
        return p;
    };
    int*    deg        = (int*)alloc(M_PAD * 4);
    int*    rs         = (int*)alloc(M_PAD * 4);
    float*  inv        = (float*)alloc(M_PAD * 4);
    int*    bucket_cnt = (int*)alloc(K_BUCK * 4);
    ushort* csr16      = (ushort*)alloc((size_t)K_BUCK * CSR_SEG * 2);
    int*    part       = (int*)alloc((size_t)K_BUCK * BUCK_CAP * 4);
    uint*   xb         = (uint*)alloc((size_t)M_PAD * 64 * 4);   // bf16 [M_PAD][128]
    uint*   t2         = (uint*)alloc((size_t)M_PAD * 32 * 4);
    uint*   u2         = (uint*)alloc((size_t)M_PAD * 32 * 4);
    ushort* B1         = (ushort*)alloc(256 * 256 * 2);
    ushort* B2         = (ushort*)alloc(128 * 256 * 2);

    hipMemsetAsync(bucket_cnt, 0, K_BUCK * sizeof(int), stream);

    entry_k<<<P_BLOCKS + PREP_ELEMS / 256, 256, 0, stream>>>(
        ei, bucket_cnt, part, (const float2*)x, xb, W1l, W1r, W2l, W2r, B1, B2);

    bag_k<<<K_BUCK, 512, 0, stream>>>(part, bucket_cnt, rs, deg, inv, csr16,
                                      xb, B1, B2, b1, (ushort*)t2, (ushort*)u2);

    final_k<<<(N_NODES + 31) / 32, 256, 0, stream>>>(rs, deg, csr16, t2, u2, b2, inv, out);
}

// Round 11
// 168.643 us; speedup vs baseline: 1.0691x; 1.0691x over previous
//
#include <hip/hip_runtime.h>
#include <hip/hip_bf16.h>

// GraphSAGE 2-layer forward, bf16-MFMA inner pipeline.
// R11: R10's fusion with the occupancy cliff fixed — LDS cut 104->69 KB so
//      2 blocks/CU (all 391 blocks co-resident, no serial tail). One HG region
//      serves as agg tile (both phase-1 halves, acc1 x2 in registers) then as
//      the per-half Hs park for phase-2. VGPR capped at 128 via launch_bounds.
// Dispatches: memset(1.5KB) -> entry -> bag -> final.

#define N_NODES 50000
#define N_EDGES 800000
#define M_PAD   50048   // 391 * 128

#define BUCK_SHIFT 7
#define K_BUCK 391            // ceil(50000/128)
#define BUCK_CAP 4096         // bucket edges: mean 2046, sigma ~45 (guarded anyway)
#define CSR_SEG 4608          // fixed per-bucket csr region (>= BUCK_CAP + 128*3 pad)
#define P1_EPB 16             // edges per thread in partition phase (4096/block)
#define P_BLOCKS 196          // ceil(800000/4096)
#define PREP_ELEMS (N_NODES * 64 + 98304)   // 3298304 = 12884*256 exactly

typedef unsigned int uint;
typedef unsigned short ushort;
typedef __attribute__((ext_vector_type(8))) short short8;
typedef __attribute__((ext_vector_type(4))) float floatx4;

__device__ __forceinline__ ushort f2bf(float f) {
    union { float f; uint u; } c; c.f = f;
    uint u = c.u;
    return (ushort)((u + 0x7FFFu + ((u >> 16) & 1u)) >> 16);  // RNE
}
__device__ __forceinline__ uint pack2(float lo, float hi) {
    return (uint)f2bf(lo) | ((uint)f2bf(hi) << 16);
}
__device__ __forceinline__ float bflo(uint v) { return __uint_as_float(v << 16); }
__device__ __forceinline__ float bfhi(uint v) { return __uint_as_float(v & 0xffff0000u); }
__device__ __forceinline__ void gload_lds16(const ushort* g, ushort* l) {
    __builtin_amdgcn_global_load_lds(
        (const __attribute__((address_space(1))) void*)g,
        (__attribute__((address_space(3))) void*)l, 16, 0, 0);
}

#define ACC8(A, v) { A[0] += bflo(v.x); A[1] += bfhi(v.x); A[2] += bflo(v.y); A[3] += bfhi(v.y); \
                     A[4] += bflo(v.z); A[5] += bfhi(v.z); A[6] += bflo(v.w); A[7] += bfhi(v.w); }

// ---------------- entry: partition (blocks < P_BLOCKS) + dtype prep ----------------

__global__ __launch_bounds__(256) void entry_k(
        const int* __restrict__ ei, int* __restrict__ bucket_cnt, int* __restrict__ part,
        const float2* __restrict__ x2, uint* __restrict__ xb,
        const float* __restrict__ W1l, const float* __restrict__ W1r,
        const float* __restrict__ W2l, const float* __restrict__ W2r,
        ushort* __restrict__ B1, ushort* __restrict__ B2) {
    __shared__ int hist[K_BUCK];
    __shared__ int goff[K_BUCK];
    const int tid = threadIdx.x;
    if (blockIdx.x < P_BLOCKS) {
        for (int i = tid; i < K_BUCK; i += 256) hist[i] = 0;
        __syncthreads();
        const int e0 = blockIdx.x * (256 * P1_EPB);
        int srcv[P1_EPB], dstv[P1_EPB];
        #pragma unroll
        for (int i = 0; i < P1_EPB; ++i) {
            int e = e0 + tid + (i << 8);
            bool ok = e < N_EDGES;
            srcv[i] = ok ? ei[e] : 0;
            dstv[i] = ok ? ei[N_EDGES + e] : -1;
            if (ok) atomicAdd(&hist[dstv[i] >> BUCK_SHIFT], 1);
        }
        __syncthreads();
        for (int b = tid; b < K_BUCK; b += 256) {
            int c = hist[b];
            goff[b] = c ? atomicAdd(&bucket_cnt[b], c) : 0;
            hist[b] = 0;                    // reuse as block-local cursor
        }
        __syncthreads();
        #pragma unroll
        for (int i = 0; i < P1_EPB; ++i) {
            if (dstv[i] >= 0) {
                int b = dstv[i] >> BUCK_SHIFT;
                int pos = goff[b] + atomicAdd(&hist[b], 1);
                if (pos < BUCK_CAP)         // memory-safety guard
                    part[(size_t)b * BUCK_CAP + pos] = srcv[i] | ((dstv[i] & 127) << 16);
            }
        }
        return;
    }
    int i = (blockIdx.x - P_BLOCKS) * 256 + tid;
    if (i < N_NODES * 64) {
        float2 v = x2[i];
        xb[i] = pack2(v.x, v.y);
        return;
    }
    int t = i - N_NODES * 64;
    if (t < 65536) {                        // B1[n][k], n<256, k<256
        int n = t >> 8, k = t & 255;
        float v = (k < 128) ? W1l[n * 128 + k] : W1r[n * 128 + (k - 128)];
        B1[t] = f2bf(v);
    } else if (t < 98304) {                 // B2[n][k], n<128, k<256
        int t2 = t - 65536;
        int n = t2 >> 8, k = t2 & 255;
        float v = (n < 64) ? W2l[n * 256 + k] : W2r[(n - 64) * 256 + k];
        B2[t2] = f2bf(v);
    }
}

// ---------------- bag: CSR build + agg (LDS tile) + fused 2-layer GEMM, 2 blk/CU ----------------
// grid = 391, 512 threads = 8 waves. LDS (ushort units):
//   HG @0     [128][136]: agg tile during phase-1 (both halves), then Hs park per half.
//   ST @17408 4 slots x [128][32] (16384): staging (A sub-panels slots 0/1 for k>=128,
//             B1 sub-panels slots 2/3; phase-2 B2-half fills all 4). csr_l aliases ST.
// acc1 kept for BOTH halves in registers (64 VGPR) so HG can be reused as Hs.
// Total LDS ~69 KB -> 2 blocks/CU; 391 blocks co-resident, no serial tail.

#define HG_STRIDE 136
#define ST_OFF 17408

__global__ __launch_bounds__(512, 4) void bag_k(
        const int* __restrict__ part, const int* __restrict__ bucket_cnt,
        int* __restrict__ rs, int* __restrict__ deg_g, float* __restrict__ inv,
        ushort* __restrict__ csr16, const uint* __restrict__ xb,
        const ushort* __restrict__ B1, const ushort* __restrict__ B2,
        const float* __restrict__ b1, ushort* __restrict__ t2,
        ushort* __restrict__ u2b) {
    __shared__ __align__(16) ushort lds[ST_OFF + 16384];
    __shared__ int degl[128], rsl[128], cur[128];
    ushort* csr_l = &lds[ST_OFF];           // alias: dead before GEMM staging begins
    const int b = blockIdx.x;
    const int tid = threadIdx.x;
    const int bm = b << 7;

    // ---- build ----
    if (tid < 128) { degl[tid] = 0; cur[tid] = 0; }
    for (int i = tid; i < CSR_SEG; i += 512) csr_l[i] = 0;
    int Eb = bucket_cnt[b]; if (Eb > BUCK_CAP) Eb = BUCK_CAP;
    const int* pe = part + (size_t)b * BUCK_CAP;
    __syncthreads();
    for (int i = tid; i < Eb; i += 512)
        atomicAdd(&degl[pe[i] >> 16], 1);
    __syncthreads();
    if (tid < 64) {                          // wave 0: exclusive scan of x4-padded degs
        int carry = 0;
        for (int c = 0; c < 128; c += 64) {
            int v = (degl[c + tid] + 3) & ~3;
            int sc = v;
            #pragma unroll
            for (int off = 1; off < 64; off <<= 1) {
                int t = __shfl_up(sc, off);
                if (tid >= off) sc += t;
            }
            rsl[c + tid] = carry + sc - v;
            carry += __shfl(sc, 63);
        }
    }
    __syncthreads();
    if (tid < 128) {
        int n = bm + tid;
        if (n < N_NODES) {
            rs[n] = b * CSR_SEG + rsl[tid];
            deg_g[n] = degl[tid];
            inv[n] = 1.0f / fmaxf((float)degl[tid], 1.0f);
        }
    }
    __syncthreads();
    for (int i = tid; i < Eb; i += 512) {
        int e = pe[i];
        int ld = e >> 16;
        int pos = atomicAdd(&cur[ld], 1);
        int o = rsl[ld] + pos;
        ushort s = (ushort)(e & 0xFFFF);
        csr_l[o] = s;
        csr16[(size_t)b * CSR_SEG + o] = s;
    }
    __syncthreads();

    // ---- gather into HG (node pairs, 8 loads in flight per 16-lane group) ----
    {
        const int g = tid >> 4, sub = tid & 15;
        #pragma unroll
        for (int v = 0; v < 4; v += 2) {
            const int ln0 = g * 4 + v, ln1 = ln0 + 1;
            const int n0 = bm + ln0, n1 = n0 + 1;
            if (n0 >= N_NODES) continue;
            const int beg0 = rsl[ln0], cnt0 = degl[ln0];
            const int beg1 = rsl[ln1], cnt1 = (n1 < N_NODES) ? degl[ln1] : 0;
            float A0[8] = {}, A1[8] = {};
            const int maxc = cnt0 > cnt1 ? cnt0 : cnt1;
            const int nR = (maxc + 3) >> 2;
            #pragma unroll 2
            for (int r = 0; r < nR; ++r) {
                uint2 i0 = *(const uint2*)&csr_l[beg0 + (r << 2)];
                uint2 i1 = *(const uint2*)&csr_l[beg1 + (r << 2)];
                uint4 v00 = *(const uint4*)(xb + (size_t)(i0.x & 0xFFFF) * 64 + (sub << 2));
                uint4 v01 = *(const uint4*)(xb + (size_t)(i0.x >> 16)    * 64 + (sub << 2));
                uint4 v02 = *(const uint4*)(xb + (size_t)(i0.y & 0xFFFF) * 64 + (sub << 2));
                uint4 v03 = *(const uint4*)(xb + (size_t)(i0.y >> 16)    * 64 + (sub << 2));
                uint4 v10 = *(const uint4*)(xb + (size_t)(i1.x & 0xFFFF) * 64 + (sub << 2));
                uint4 v11 = *(const uint4*)(xb + (size_t)(i1.x >> 16)    * 64 + (sub << 2));
                uint4 v12 = *(const uint4*)(xb + (size_t)(i1.y & 0xFFFF) * 64 + (sub << 2));
                uint4 v13 = *(const uint4*)(xb + (size_t)(i1.y >> 16)    * 64 + (sub << 2));
                int e0 = r << 2;
                if (e0 + 0 < cnt0) ACC8(A0, v00);
                if (e0 + 1 < cnt0) ACC8(A0, v01);
                if (e0 + 2 < cnt0) ACC8(A0, v02);
                if (e0 + 3 < cnt0) ACC8(A0, v03);
                if (e0 + 0 < cnt1) ACC8(A1, v10);
                if (e0 + 1 < cnt1) ACC8(A1, v11);
                if (e0 + 2 < cnt1) ACC8(A1, v12);
                if (e0 + 3 < cnt1) ACC8(A1, v13);
            }
            {
                const float w = 1.0f / fmaxf((float)cnt0, 1.0f);
                uint4 o;
                o.x = pack2(A0[0] * w, A0[1] * w); o.y = pack2(A0[2] * w, A0[3] * w);
                o.z = pack2(A0[4] * w, A0[5] * w); o.w = pack2(A0[6] * w, A0[7] * w);
                *(uint4*)((uint*)&lds[ln0 * HG_STRIDE] + (sub << 2)) = o;
            }
            if (n1 < N_NODES) {
                const float w = 1.0f / fmaxf((float)cnt1, 1.0f);
                uint4 o;
                o.x = pack2(A1[0] * w, A1[1] * w); o.y = pack2(A1[2] * w, A1[3] * w);
                o.z = pack2(A1[4] * w, A1[5] * w); o.w = pack2(A1[6] * w, A1[7] * w);
                *(uint4*)((uint*)&lds[ln1 * HG_STRIDE] + (sub << 2)) = o;
            }
        }
    }
    __syncthreads();                          // HG (agg tile) ready; csr_l dead

    // ---- fused 2-layer GEMM ----
    const int w8 = tid >> 6, lane = tid & 63;
    const int q = lane >> 4, mr = lane & 15;
    const int wm = (w8 & 1) << 6;             // wave rows 0/64
    const int wn = (w8 >> 1) << 5;            // wave cols 0/32/64/96
    const int srow = tid >> 2;                // staging row 0..127
    const int scol = (tid & 3) << 3;          // ushort offset within 32-wide panel

    floatx4 acc1[2][4][2];                    // both halves live (HG stays agg until phase-2)
    floatx4 acc2[4][2];
    #pragma unroll
    for (int i = 0; i < 4; ++i)
        #pragma unroll
        for (int j = 0; j < 2; ++j) {
            acc1[0][i][j] = (floatx4){0.f, 0.f, 0.f, 0.f};
            acc1[1][i][j] = (floatx4){0.f, 0.f, 0.f, 0.f};
            acc2[i][j] = (floatx4){0.f, 0.f, 0.f, 0.f};
        }

    // phase-1: both halves; BK=64 iterations of 2x32 sub-panels
    #pragma unroll
    for (int h = 0; h < 2; ++h) {
        #pragma unroll
        for (int k0i = 0; k0i < 4; ++k0i) {
            const int k0 = k0i << 6;
            if (k0 >= 128) {                  // A sub-panels from xb -> slots 0,1
                #pragma unroll
                for (int p = 0; p < 2; ++p)
                    gload_lds16((const ushort*)xb + (size_t)(bm + srow) * 128 + (k0 - 128) + (p << 5) + scol,
                                lds + ST_OFF + (p << 12) + srow * 32 + scol);
            }
            #pragma unroll
            for (int p = 0; p < 2; ++p)       // B1 sub-panels -> slots 2,3
                gload_lds16(B1 + (size_t)((h << 7) + srow) * 256 + k0 + (p << 5) + scol,
                            lds + ST_OFF + 8192 + (p << 12) + srow * 32 + scol);
            __syncthreads();
            #pragma unroll
            for (int p = 0; p < 2; ++p) {
                short8 af[4], bfr[2];
                if (k0 < 128) {               // A from HG (agg tile), col k0+p*32
                    #pragma unroll
                    for (int i = 0; i < 4; ++i)
                        af[i] = *(const short8*)&lds[(wm + (i << 4) + mr) * HG_STRIDE + k0 + (p << 5) + (q << 3)];
                } else {
                    #pragma unroll
                    for (int i = 0; i < 4; ++i)
                        af[i] = *(const short8*)&lds[ST_OFF + (p << 12) + (wm + (i << 4) + mr) * 32 + (q << 3)];
                }
                #pragma unroll
                for (int j = 0; j < 2; ++j)
                    bfr[j] = *(const short8*)&lds[ST_OFF + 8192 + (p << 12) + (wn + (j << 4) + mr) * 32 + (q << 3)];
                #pragma unroll
                for (int i = 0; i < 4; ++i)
                    #pragma unroll
                    for (int j = 0; j < 2; ++j)
                        acc1[h][i][j] = __builtin_amdgcn_mfma_f32_16x16x32_bf16(af[i], bfr[j], acc1[h][i][j], 0, 0, 0);
            }
            __syncthreads();
        }
    }
    // phase-2: per half, Hs park into HG (agg now dead) + B2-half staged into ST
    #pragma unroll
    for (int h = 0; h < 2; ++h) {
        #pragma unroll
        for (int p2 = 0; p2 < 4; ++p2)        // B2-half -> all 4 slots (overlaps epilogue)
            gload_lds16(B2 + (size_t)srow * 256 + (h << 7) + (p2 << 5) + scol,
                        lds + ST_OFF + (p2 << 12) + srow * 32 + scol);
        #pragma unroll
        for (int i = 0; i < 4; ++i) {         // epilogue 1: relu+bias -> HG (bf16)
            int row = wm + (i << 4) + (q << 2);
            #pragma unroll
            for (int j = 0; j < 2; ++j) {
                int col = wn + (j << 4) + mr;
                float bv = b1[(h << 7) + col];
                #pragma unroll
                for (int r = 0; r < 4; ++r) {
                    float v = fmaxf(acc1[h][i][j][r] + bv, 0.f);
                    lds[(row + r) * HG_STRIDE + col] = f2bf(v);
                }
            }
        }
        __syncthreads();
        #pragma unroll
        for (int p2 = 0; p2 < 4; ++p2) {      // acc2 += Hs @ B2half^T
            short8 af2[4], bf2[2];
            #pragma unroll
            for (int i = 0; i < 4; ++i)
                af2[i] = *(const short8*)&lds[(wm + (i << 4) + mr) * HG_STRIDE + (p2 << 5) + (q << 3)];
            #pragma unroll
            for (int j = 0; j < 2; ++j)
                bf2[j] = *(const short8*)&lds[ST_OFF + (p2 << 12) + (wn + (j << 4) + mr) * 32 + (q << 3)];
            #pragma unroll
            for (int i = 0; i < 4; ++i)
                #pragma unroll
                for (int j = 0; j < 2; ++j)
                    acc2[i][j] = __builtin_amdgcn_mfma_f32_16x16x32_bf16(af2[i], bf2[j], acc2[i][j], 0, 0, 0);
        }
        __syncthreads();                      // HG/ST free before next half
    }
    // ---- epilogue 2: t2 (cols 0..63) | u2 (cols 64..127), both bf16 ----
    #pragma unroll
    for (int i = 0; i < 4; ++i) {
        int row = bm + wm + (i << 4) + (q << 2);
        #pragma unroll
        for (int j = 0; j < 2; ++j) {
            int col = wn + (j << 4) + mr;
            #pragma unroll
            for (int r = 0; r < 4; ++r) {
                float v = acc2[i][j][r];
                if (col < 64) t2[(size_t)(row + r) * 64 + col] = f2bf(v);
                else          u2b[(size_t)(row + r) * 64 + (col - 64)] = f2bf(v);
            }
        }
    }
}

// ---------------- final: group-per-node (8 lanes), broadcast idx, no reduce ----------------

__global__ __launch_bounds__(256) void final_k(
        const int* __restrict__ rs, const int* __restrict__ deg,
        const ushort* __restrict__ csr16, const uint* __restrict__ t2,
        const uint* __restrict__ u2, const float* __restrict__ b2,
        const float* __restrict__ inv, float* __restrict__ out) {
    const int tid = threadIdx.x, lane = tid & 63, wid = tid >> 6;
    const int g = lane >> 3, sub = lane & 7;
    const int n = blockIdx.x * 32 + wid * 8 + g;
    if (n >= N_NODES) return;
    const int beg = rs[n], cnt = deg[n];
    float A[8] = {};
    const int nR = (cnt + 3) >> 2;
    #pragma unroll 4
    for (int r = 0; r < nR; ++r) {
        uint2 i2 = *(const uint2*)(csr16 + beg + (r << 2));     // 4 src ids, broadcast
        int s0 = i2.x & 0xFFFF, s1 = i2.x >> 16;
        int s2 = i2.y & 0xFFFF, s3 = i2.y >> 16;
        uint4 v0 = *(const uint4*)(t2 + (size_t)s0 * 32 + (sub << 2));
        uint4 v1 = *(const uint4*)(t2 + (size_t)s1 * 32 + (sub << 2));
        uint4 v2 = *(const uint4*)(t2 + (size_t)s2 * 32 + (sub << 2));
        uint4 v3 = *(const uint4*)(t2 + (size_t)s3 * 32 + (sub << 2));
        int e0 = r << 2;
        if (e0 + 0 < cnt) ACC8(A, v0);
        if (e0 + 1 < cnt) ACC8(A, v1);
        if (e0 + 2 < cnt) ACC8(A, v2);
        if (e0 + 3 < cnt) ACC8(A, v3);
    }
    const float w = inv[n];
    uint4 ur = *(const uint4*)(u2 + (size_t)n * 32 + (sub << 2));
    const float* br = b2 + (sub << 3);
    float4 o0, o1;
    o0.x = bflo(ur.x) + br[0] + A[0] * w;
    o0.y = bfhi(ur.x) + br[1] + A[1] * w;
    o0.z = bflo(ur.y) + br[2] + A[2] * w;
    o0.w = bfhi(ur.y) + br[3] + A[3] * w;
    o1.x = bflo(ur.z) + br[4] + A[4] * w;
    o1.y = bfhi(ur.z) + br[5] + A[5] * w;
    o1.z = bflo(ur.w) + br[6] + A[6] * w;
    o1.w = bfhi(ur.w) + br[7] + A[7] * w;
    float* orow = out + (size_t)n * 64 + (sub << 3);
    *(float4*)orow = o0;
    *(float4*)(orow + 4) = o1;
}

// ---------------- launch ----------------

extern "C" void kernel_launch(void* const* d_in, const int* in_sizes, int n_in,
                              void* d_out, int out_size, void* d_ws, size_t ws_size,
                              hipStream_t stream) {
    const float* x   = (const float*)d_in[0];
    const int*   ei  = (const int*)d_in[1];
    const float* W1l = (const float*)d_in[2];
    const float* W1r = (const float*)d_in[3];
    const float* b1  = (const float*)d_in[4];
    const float* W2l = (const float*)d_in[5];
    const float* W2r = (const float*)d_in[6];
    const float* b2  = (const float*)d_in[7];
    float* out = (float*)d_out;

    char* base = (char*)d_ws;
    size_t off = 0;
    auto alloc = [&](size_t bytes) -> void* {
        void* p = base + off;
        off = (off + bytes + 255) & ~(size_t)255;
        return p;
    };
    int*    deg        = (int*)alloc(M_PAD * 4);
    int*    rs         = (int*)alloc(M_PAD * 4);
    float*  inv        = (float*)alloc(M_PAD * 4);
    int*    bucket_cnt = (int*)alloc(K_BUCK * 4);
    ushort* csr16      = (ushort*)alloc((size_t)K_BUCK * CSR_SEG * 2);
    int*    part       = (int*)alloc((size_t)K_BUCK * BUCK_CAP * 4);
    uint*   xb         = (uint*)alloc((size_t)M_PAD * 64 * 4);   // bf16 [M_PAD][128]
    uint*   t2         = (uint*)alloc((size_t)M_PAD * 32 * 4);
    uint*   u2         = (uint*)alloc((size_t)M_PAD * 32 * 4);
    ushort* B1         = (ushort*)alloc(256 * 256 * 2);
    ushort* B2         = (ushort*)alloc(128 * 256 * 2);

    hipMemsetAsync(bucket_cnt, 0, K_BUCK * sizeof(int), stream);

    entry_k<<<P_BLOCKS + PREP_ELEMS / 256, 256, 0, stream>>>(
        ei, bucket_cnt, part, (const float2*)x, xb, W1l, W1r, W2l, W2r, B1, B2);

    bag_k<<<K_BUCK, 512, 0, stream>>>(part, bucket_cnt, rs, deg, inv, csr16,
                                      xb, B1, B2, b1, (ushort*)t2, (ushort*)u2);

    final_k<<<(N_NODES + 31) / 32, 256, 0, stream>>>(rs, deg, csr16, t2, u2, b2, inv, out);
}